// Round 1
// baseline (370.464 us; speedup 1.0000x reference)
//
#include <hip/hip_runtime.h>

// Problem constants
#define BB 256
#define LL 500
#define EE 300
#define HH 10
#define KK 5

#define NT 512          // threads per block (8 waves)
#define CE 60           // e-chunk size
#define NCH (EE / CE)   // 5 chunks
#define LP 61           // padded LDS row stride (words) -> conflict-free column reads

__global__ __launch_bounds__(NT, 1) void anr_fused(
    const float* __restrict__ review,    // (B, L, E)
    const float* __restrict__ aspProj,   // (K, E, H)
    const float* __restrict__ aspEmbed,  // (K, 3H) feature layout f = h*3 + offset
    float* __restrict__ out)             // [attn (B,K,L)] ++ [rep (B,K,H)]
{
    __shared__ float s_rev[NT * LP];        // ~125 KB, reused as s_d later
    __shared__ float s_red[KK * 8];         // per-wave softmax partials
    __shared__ float s_rep[8 * KK * HH];    // per-wave rep partials

    const int tid  = threadIdx.x;
    const int b    = blockIdx.x;
    const int l    = tid;
    const int lane = tid & 63;
    const int wid  = tid >> 6;

    float acc[KK * HH];
#pragma unroll
    for (int i = 0; i < KK * HH; ++i) acc[i] = 0.f;

    // zero-fill pad rows l = 500..511 so pad threads accumulate clean zeros
    for (int i = tid; i < (NT - LL) * LP; i += NT) {
        int r = i / LP, c = i % LP;
        s_rev[(LL + r) * LP + c] = 0.f;
    }

    const float4* rev4 = (const float4*)review + (size_t)b * LL * (EE / 4);

    // ---- main GEMM: proj[l][k][h] = sum_e review[b][l][e] * aspProj[k][e][h] ----
    for (int ch = 0; ch < NCH; ++ch) {
        __syncthreads();
        for (int j = tid; j < LL * (CE / 4); j += NT) {
            int ll = j / (CE / 4);
            int q  = j % (CE / 4);
            float4 v = rev4[ll * (EE / 4) + ch * (CE / 4) + q];
            float* dst = &s_rev[ll * LP + 4 * q];
            dst[0] = v.x; dst[1] = v.y; dst[2] = v.z; dst[3] = v.w;
        }
        __syncthreads();

        const float* Ap = aspProj + ch * CE * HH;
#pragma unroll 10
        for (int ee = 0; ee < CE; ++ee) {
            float r = s_rev[l * LP + ee];
#pragma unroll
            for (int k = 0; k < KK; ++k) {
#pragma unroll
                for (int h = 0; h < HH; ++h) {
                    acc[k * HH + h] = fmaf(r, Ap[k * EE * HH + ee * HH + h], acc[k * HH + h]);
                }
            }
        }
    }

    // ---- window dots ----
    float d0[KK], d1[KK], d2[KK];
#pragma unroll
    for (int k = 0; k < KK; ++k) {
        float a0 = 0.f, a1 = 0.f, a2 = 0.f;
#pragma unroll
        for (int h = 0; h < HH; ++h) {
            float a = acc[k * HH + h];
            a0 = fmaf(a, aspEmbed[k * 3 * HH + 3 * h + 0], a0);
            a1 = fmaf(a, aspEmbed[k * 3 * HH + 3 * h + 1], a1);
            a2 = fmaf(a, aspEmbed[k * 3 * HH + 3 * h + 2], a2);
        }
        d0[k] = a0; d1[k] = a1; d2[k] = a2;
    }

    __syncthreads();
    float* s_d = s_rev;              // reuse: [o][k][NT]
#pragma unroll
    for (int k = 0; k < KK; ++k) {
        s_d[(0 * KK + k) * NT + tid] = d0[k];
        s_d[(1 * KK + k) * NT + tid] = d1[k];
        s_d[(2 * KK + k) * NT + tid] = d2[k];
    }
    __syncthreads();

    float sc[KK];
#pragma unroll
    for (int k = 0; k < KK; ++k) {
        float t0 = (l >= 1)     ? s_d[(0 * KK + k) * NT + l - 1] : 0.f;
        float t1 =                s_d[(1 * KK + k) * NT + l];
        float t2 = (l + 1 < LL) ? s_d[(2 * KK + k) * NT + l + 1] : 0.f;
        sc[k] = (l < LL) ? (t0 + t1 + t2) : -1e30f;
    }

    // ---- softmax over L ----
    float mx[KK], ex[KK], sm[KK];
#pragma unroll
    for (int k = 0; k < KK; ++k) {
        float m = sc[k];
        for (int s = 32; s > 0; s >>= 1) m = fmaxf(m, __shfl_xor(m, s, 64));
        if (lane == 0) s_red[k * 8 + wid] = m;
    }
    __syncthreads();
#pragma unroll
    for (int k = 0; k < KK; ++k) {
        float m = s_red[k * 8];
#pragma unroll
        for (int w = 1; w < 8; ++w) m = fmaxf(m, s_red[k * 8 + w]);
        mx[k] = m;
    }
    __syncthreads();
#pragma unroll
    for (int k = 0; k < KK; ++k) {
        ex[k] = __expf(sc[k] - mx[k]);
        float s = ex[k];
        for (int sh = 32; sh > 0; sh >>= 1) s += __shfl_xor(s, sh, 64);
        if (lane == 0) s_red[k * 8 + wid] = s;
    }
    __syncthreads();
#pragma unroll
    for (int k = 0; k < KK; ++k) {
        float s = 0.f;
#pragma unroll
        for (int w = 0; w < 8; ++w) s += s_red[k * 8 + w];
        sm[k] = s;
    }

    float attn[KK];
#pragma unroll
    for (int k = 0; k < KK; ++k) {
        attn[k] = ex[k] / sm[k];
        if (l < LL) out[((size_t)b * KK + k) * LL + l] = attn[k];
    }

    // ---- rep[k][h] = sum_l proj * attn ----
#pragma unroll
    for (int k = 0; k < KK; ++k) {
#pragma unroll
        for (int h = 0; h < HH; ++h) {
            float v = acc[k * HH + h] * attn[k];
            for (int sh = 32; sh > 0; sh >>= 1) v += __shfl_xor(v, sh, 64);
            if (lane == 0) s_rep[wid * (KK * HH) + k * HH + h] = v;
        }
    }
    __syncthreads();
    if (tid < KK * HH) {
        float s = 0.f;
#pragma unroll
        for (int w = 0; w < 8; ++w) s += s_rep[w * (KK * HH) + tid];
        out[(size_t)BB * KK * LL + (size_t)b * (KK * HH) + tid] = s;
    }
}

extern "C" void kernel_launch(void* const* d_in, const int* in_sizes, int n_in,
                              void* d_out, int out_size, void* d_ws, size_t ws_size,
                              hipStream_t stream) {
    const float* review   = (const float*)d_in[0];  // (B,L,E)
    const float* aspProj  = (const float*)d_in[1];  // (K,E,H)
    const float* aspEmbed = (const float*)d_in[2];  // (K,3H)
    float* out = (float*)d_out;

    anr_fused<<<dim3(BB), dim3(NT), 0, stream>>>(review, aspProj, aspEmbed, out);
}

// Round 2
// 294.247 us; speedup vs baseline: 1.2590x; 1.2590x over previous
//
#include <hip/hip_runtime.h>

// Problem constants
#define BB 256
#define LL 500
#define EE 300
#define HH 10
#define KK 5
#define NF (KK * HH)     // 50 output features per l

#define NT 256           // threads per block (4 waves); each thread owns 2 seq positions
#define NT2 512          // 2*NT, covers L=500 with 12 pad slots
#define NW (NT / 64)     // 4 waves
#define ALP 52           // padded asp row stride (floats) = 13 float4, 16B-aligned rows

__global__ __launch_bounds__(NT, 1) void anr_fused2(
    const float* __restrict__ review,    // (B, L, E)
    const float* __restrict__ aspProj,   // (K, E, H)
    const float* __restrict__ aspEmbed,  // (K, 3H), f = h*3 + offset
    float* __restrict__ out)             // [attn (B,K,L)] ++ [rep (B,K,H)]
{
    __shared__ float aspL[EE * ALP];     // 62.4 KB; reused as s_d[3*KK*NT2] after GEMM
    __shared__ float s_red[KK * NW];
    __shared__ float s_rep[NW * NF];

    const int tid  = threadIdx.x;
    const int b    = blockIdx.x;
    const int lane = tid & 63;
    const int wid  = tid >> 6;
    const int l0   = tid;                // 0..255  (always < LL)
    const int l1   = tid + NT;           // 256..511
    const bool v1  = (l1 < LL);

    // ---- stage aspProj -> LDS, layout [ee][k*HH+h], once ----
    for (int j = tid; j < KK * EE * HH; j += NT) {
        int k  = j / (EE * HH);
        int r  = j - k * (EE * HH);
        int ee = r / HH;
        int h  = r - ee * HH;
        aspL[ee * ALP + k * HH + h] = aspProj[j];
    }
    __syncthreads();

    // ---- GEMM: acc[l][k*H+h] = sum_e review[b][l][e] * asp[e][k*H+h] ----
    float acc0[NF], acc1[NF];
#pragma unroll
    for (int i = 0; i < NF; ++i) { acc0[i] = 0.f; acc1[i] = 0.f; }

    const float4* row0v = (const float4*)(review + ((size_t)b * LL + l0) * EE);
    const int l1c = v1 ? l1 : (LL - 1);  // clamp; acc1 discarded for invalid l1
    const float4* row1v = (const float4*)(review + ((size_t)b * LL + l1c) * EE);

#pragma unroll 2
    for (int e4 = 0; e4 < EE / 4; ++e4) {
        float4 r0 = row0v[e4];           // own row: vmcnt, pipelined by compiler
        float4 r1 = row1v[e4];
        float rr0[4] = {r0.x, r0.y, r0.z, r0.w};
        float rr1[4] = {r1.x, r1.y, r1.z, r1.w};
#pragma unroll
        for (int u = 0; u < 4; ++u) {
            const float4* a4 = (const float4*)&aspL[(e4 * 4 + u) * ALP];
            float m0 = rr0[u], m1 = rr1[u];
#pragma unroll
            for (int j4 = 0; j4 < 13; ++j4) {
                float4 a = a4[j4];       // broadcast ds_read_b128, in-order lgkmcnt
                int base = j4 * 4;
                if (base + 0 < NF) { acc0[base+0] = fmaf(m0, a.x, acc0[base+0]);
                                     acc1[base+0] = fmaf(m1, a.x, acc1[base+0]); }
                if (base + 1 < NF) { acc0[base+1] = fmaf(m0, a.y, acc0[base+1]);
                                     acc1[base+1] = fmaf(m1, a.y, acc1[base+1]); }
                if (base + 2 < NF) { acc0[base+2] = fmaf(m0, a.z, acc0[base+2]);
                                     acc1[base+2] = fmaf(m1, a.z, acc1[base+2]); }
                if (base + 3 < NF) { acc0[base+3] = fmaf(m0, a.w, acc0[base+3]);
                                     acc1[base+3] = fmaf(m1, a.w, acc1[base+3]); }
            }
        }
    }

    // ---- window dots: d_o[l][k] = sum_h proj[l][k][h] * aspEmbed[k][3h+o] ----
    float d0a[KK], d1a[KK], d2a[KK], d0b[KK], d1b[KK], d2b[KK];
#pragma unroll
    for (int k = 0; k < KK; ++k) {
        float a0 = 0.f, a1 = 0.f, a2 = 0.f, b0 = 0.f, b1 = 0.f, b2 = 0.f;
#pragma unroll
        for (int h = 0; h < HH; ++h) {
            float e0 = aspEmbed[k * 3 * HH + 3 * h + 0];
            float e1 = aspEmbed[k * 3 * HH + 3 * h + 1];
            float e2 = aspEmbed[k * 3 * HH + 3 * h + 2];
            float x0 = acc0[k * HH + h], x1 = acc1[k * HH + h];
            a0 = fmaf(x0, e0, a0); a1 = fmaf(x0, e1, a1); a2 = fmaf(x0, e2, a2);
            b0 = fmaf(x1, e0, b0); b1 = fmaf(x1, e1, b1); b2 = fmaf(x1, e2, b2);
        }
        d0a[k] = a0; d1a[k] = a1; d2a[k] = a2;
        d0b[k] = v1 ? b0 : 0.f;          // pad rows contribute zeros
        d1b[k] = v1 ? b1 : 0.f;
        d2b[k] = v1 ? b2 : 0.f;
    }

    __syncthreads();                     // done reading aspL
    float* s_d = aspL;                   // reuse: [o][k][NT2]
#pragma unroll
    for (int k = 0; k < KK; ++k) {
        s_d[(0 * KK + k) * NT2 + l0] = d0a[k];
        s_d[(1 * KK + k) * NT2 + l0] = d1a[k];
        s_d[(2 * KK + k) * NT2 + l0] = d2a[k];
        s_d[(0 * KK + k) * NT2 + l1] = d0b[k];
        s_d[(1 * KK + k) * NT2 + l1] = d1b[k];
        s_d[(2 * KK + k) * NT2 + l1] = d2b[k];
    }
    __syncthreads();

    // scores[l] = d0[l-1] + d1[l] + d2[l+1]
    float sc0[KK], sc1[KK];
#pragma unroll
    for (int k = 0; k < KK; ++k) {
        float t0 = (l0 >= 1) ? s_d[(0 * KK + k) * NT2 + l0 - 1] : 0.f;
        float t1 = s_d[(1 * KK + k) * NT2 + l0];
        float t2 = s_d[(2 * KK + k) * NT2 + l0 + 1];   // l0+1 <= 256, zeros at pads
        sc0[k] = t0 + t1 + t2;
        if (v1) {
            float u0 = s_d[(0 * KK + k) * NT2 + l1 - 1];
            float u1 = s_d[(1 * KK + k) * NT2 + l1];
            float u2 = s_d[(2 * KK + k) * NT2 + l1 + 1]; // l1+1 <= 500, s_d[500]=0
            sc1[k] = u0 + u1 + u2;
        } else {
            sc1[k] = -1e30f;
        }
    }

    // ---- softmax over L per k ----
    float mx[KK];
#pragma unroll
    for (int k = 0; k < KK; ++k) {
        float m = fmaxf(sc0[k], sc1[k]);
        for (int s = 32; s > 0; s >>= 1) m = fmaxf(m, __shfl_xor(m, s, 64));
        if (lane == 0) s_red[k * NW + wid] = m;
    }
    __syncthreads();
#pragma unroll
    for (int k = 0; k < KK; ++k) {
        float m = s_red[k * NW + 0];
#pragma unroll
        for (int w = 1; w < NW; ++w) m = fmaxf(m, s_red[k * NW + w]);
        mx[k] = m;
    }
    __syncthreads();
    float ex0[KK], ex1[KK], sm[KK];
#pragma unroll
    for (int k = 0; k < KK; ++k) {
        ex0[k] = __expf(sc0[k] - mx[k]);
        ex1[k] = __expf(sc1[k] - mx[k]);   // invalid l1: exp(-huge) = 0
        float s = ex0[k] + ex1[k];
        for (int sh = 32; sh > 0; sh >>= 1) s += __shfl_xor(s, sh, 64);
        if (lane == 0) s_red[k * NW + wid] = s;
    }
    __syncthreads();
#pragma unroll
    for (int k = 0; k < KK; ++k) {
        float s = 0.f;
#pragma unroll
        for (int w = 0; w < NW; ++w) s += s_red[k * NW + w];
        sm[k] = s;
    }

    // ---- attn writes + rep reduction ----
#pragma unroll
    for (int k = 0; k < KK; ++k) {
        float w0 = ex0[k] / sm[k];
        float w1 = ex1[k] / sm[k];         // 0 for invalid l1
        out[((size_t)b * KK + k) * LL + l0] = w0;
        if (v1) out[((size_t)b * KK + k) * LL + l1] = w1;
#pragma unroll
        for (int h = 0; h < HH; ++h) {
            float v = acc0[k * HH + h] * w0 + acc1[k * HH + h] * w1;
            for (int sh = 32; sh > 0; sh >>= 1) v += __shfl_xor(v, sh, 64);
            if (lane == 0) s_rep[wid * NF + k * HH + h] = v;
        }
    }
    __syncthreads();
    if (tid < NF) {
        float s = 0.f;
#pragma unroll
        for (int w = 0; w < NW; ++w) s += s_rep[w * NF + tid];
        out[(size_t)BB * KK * LL + (size_t)b * NF + tid] = s;
    }
}

extern "C" void kernel_launch(void* const* d_in, const int* in_sizes, int n_in,
                              void* d_out, int out_size, void* d_ws, size_t ws_size,
                              hipStream_t stream) {
    const float* review   = (const float*)d_in[0];  // (B,L,E)
    const float* aspProj  = (const float*)d_in[1];  // (K,E,H)
    const float* aspEmbed = (const float*)d_in[2];  // (K,3H)
    float* out = (float*)d_out;

    anr_fused2<<<dim3(BB), dim3(NT), 0, stream>>>(review, aspProj, aspEmbed, out);
}

// Round 3
// 248.744 us; speedup vs baseline: 1.4893x; 1.1829x over previous
//
#include <hip/hip_runtime.h>

#define BB 256
#define LL 500
#define EE 300
#define HH 10
#define KK 5
#define NF 50          // K*H output features
#define NT 512         // 8 waves
#define NWAVE 8

#define MP 512         // padded M (rows per batch)
#define CK 64          // K-chunk (e) per stage
#define NCH 5          // 300/64 -> 5 chunks (last partial, zero-padded to 320)
#define AP 72          // A_lds row stride (bf16): 64 + 8 pad -> 2-way banks (free)
#define BP 328         // Bt row stride (bf16): 320 + 8 pad
#define PP 53          // proj row stride (floats): odd -> conflict-free column walk

// LDS overlay (bytes)
#define A_BYTES   (MP * AP * 2)            // 73728
#define B_OFF     A_BYTES                  // Bt at 73728, 64*328*2 = 41984 (ends 115712)
#define SD_OFF    (MP * PP * 4)            // proj [0,108544); s_d after it
#define RED_OFF   (SD_OFF + 3 * KK * MP * 4)   // 108544+30720 = 139264
#define REP_OFF   (RED_OFF + KK * NWAVE * 4)
#define EMB_OFF   (REP_OFF + NWAVE * NF * 4)
#define SMEM_BYTES (EMB_OFF + KK * 3 * HH * 4) // 141624 < 163840

typedef __attribute__((ext_vector_type(8))) short short8;
typedef __attribute__((ext_vector_type(4))) float f32x4;

__device__ __forceinline__ unsigned short f2bf(float x) {
    // round-to-nearest-even fp32 -> bf16
    unsigned int u = __float_as_uint(x);
    return (unsigned short)((u + 0x7FFFu + ((u >> 16) & 1u)) >> 16);
}

__global__ __launch_bounds__(NT, 2) void anr_mfma(
    const float* __restrict__ review,    // (B, L, E)
    const float* __restrict__ aspProj,   // (K, E, H)
    const float* __restrict__ aspEmbed,  // (K, 3H), f = h*3 + offset
    float* __restrict__ out)             // [attn (B,K,L)] ++ [rep (B,K,H)]
{
    __shared__ __align__(16) char smem[SMEM_BYTES];
    short* A16   = (short*)smem;                 // bf16 A chunk [512][AP]
    short* B16   = (short*)(smem + B_OFF);       // bf16 Bt [64][BP]
    float* proj  = (float*)smem;                 // fp32 proj [512][PP] (epilogue)
    float* s_d   = (float*)(smem + SD_OFF);      // [3][KK][512]
    float* s_red = (float*)(smem + RED_OFF);
    float* s_rep = (float*)(smem + REP_OFF);
    float* s_emb = (float*)(smem + EMB_OFF);     // aspEmbed copy (150 floats)

    const int tid  = threadIdx.x;
    const int b    = blockIdx.x;
    const int lane = tid & 63;
    const int w    = tid >> 6;          // wave id 0..7 -> M rows [w*64, w*64+64)
    const int quad = lane >> 4;         // 0..3
    const int m16  = lane & 15;

    // ---- prologue: zero Bt (incl. k-pad & n-pad), copy aspEmbed to LDS ----
    for (int j = tid; j < (64 * BP * 2) / 4; j += NT)
        ((int*)(smem + B_OFF))[j] = 0;
    if (tid < KK * 3 * HH) s_emb[tid] = aspEmbed[tid];
    __syncthreads();

    // fire chunk-0 review loads, then fill Bt (overlaps with loads in flight)
    const float4* rev4 = (const float4*)review + (size_t)b * LL * (EE / 4);
    const int q  = tid & 15;            // float4 column within chunk
    const int r0 = tid >> 4;            // base row
    float4 pre[16];
#pragma unroll
    for (int i = 0; i < 16; ++i) {
        int r = 32 * i + r0;
        float4 z = {0.f, 0.f, 0.f, 0.f};
        pre[i] = (r < LL && q < EE / 4) ? rev4[(size_t)r * (EE / 4) + q] : z;
    }
    for (int j = tid; j < KK * EE * HH; j += NT) {
        int kasp = j / (EE * HH);
        int rr   = j - kasp * (EE * HH);
        int e    = rr / HH;
        int h    = rr - e * HH;
        B16[(kasp * HH + h) * BP + e] = (short)f2bf(aspProj[j]);
    }

    // ---- GEMM main loop: proj[512x50] = A[512x320] * B[320x64] ----
    f32x4 acc[4][4];
#pragma unroll
    for (int mi = 0; mi < 4; ++mi)
#pragma unroll
        for (int ni = 0; ni < 4; ++ni)
            acc[mi][ni] = (f32x4){0.f, 0.f, 0.f, 0.f};

    for (int c = 0; c < NCH; ++c) {
        __syncthreads();                 // A_lds free (prev chunk's reads done) + pre arrived
        // store pre -> A_lds as bf16
#pragma unroll
        for (int i = 0; i < 16; ++i) {
            int r = 32 * i + r0;
            float4 v = pre[i];
            uint2 pk;
            pk.x = (unsigned)f2bf(v.x) | ((unsigned)f2bf(v.y) << 16);
            pk.y = (unsigned)f2bf(v.z) | ((unsigned)f2bf(v.w) << 16);
            *(uint2*)&A16[r * AP + q * 4] = pk;
        }
        __syncthreads();
        // prefetch next chunk AFTER the barrier so loads overlap the mfma phase
        if (c + 1 < NCH) {
#pragma unroll
            for (int i = 0; i < 16; ++i) {
                int r  = 32 * i + r0;
                int fq = (c + 1) * 16 + q;
                float4 z = {0.f, 0.f, 0.f, 0.f};
                pre[i] = (r < LL && fq < EE / 4) ? rev4[(size_t)r * (EE / 4) + fq] : z;
            }
        }
        // compute: 2 k-steps of 32
#pragma unroll
        for (int s = 0; s < 2; ++s) {
            short8 af[4], bf[4];
#pragma unroll
            for (int mi = 0; mi < 4; ++mi)
                af[mi] = *(const short8*)&A16[(w * 64 + mi * 16 + m16) * AP + s * 32 + quad * 8];
#pragma unroll
            for (int ni = 0; ni < 4; ++ni)
                bf[ni] = *(const short8*)&B16[(ni * 16 + m16) * BP + c * 64 + s * 32 + quad * 8];
#pragma unroll
            for (int mi = 0; mi < 4; ++mi)
#pragma unroll
                for (int ni = 0; ni < 4; ++ni)
                    acc[mi][ni] = __builtin_amdgcn_mfma_f32_16x16x32_bf16(
                        af[mi], bf[ni], acc[mi][ni], 0, 0, 0);
        }
    }

    // ---- C fragments -> proj LDS (C/D: col = lane&15, row = quad*4 + reg) ----
    __syncthreads();
#pragma unroll
    for (int mi = 0; mi < 4; ++mi) {
#pragma unroll
        for (int ni = 0; ni < 4; ++ni) {
            int col = ni * 16 + m16;
            if (col < NF) {
                int row = w * 64 + mi * 16 + quad * 4;
#pragma unroll
                for (int r = 0; r < 4; ++r)
                    proj[(row + r) * PP + col] = acc[mi][ni][r];
            }
        }
    }
    __syncthreads();

    // ---- epilogue: thread = one sequence position l ----
    const int l  = tid;
    const bool vl = (l < LL);            // pad rows have proj == 0 exactly

    float pr[NF];
#pragma unroll
    for (int f = 0; f < NF; ++f) pr[f] = proj[l * PP + f];

    float d0[KK], d1[KK], d2[KK];
#pragma unroll
    for (int k = 0; k < KK; ++k) {
        float a0 = 0.f, a1 = 0.f, a2 = 0.f;
#pragma unroll
        for (int h = 0; h < HH; ++h) {
            float x  = pr[k * HH + h];
            a0 = fmaf(x, s_emb[k * 3 * HH + 3 * h + 0], a0);
            a1 = fmaf(x, s_emb[k * 3 * HH + 3 * h + 1], a1);
            a2 = fmaf(x, s_emb[k * 3 * HH + 3 * h + 2], a2);
        }
        d0[k] = a0; d1[k] = a1; d2[k] = a2;
    }
#pragma unroll
    for (int k = 0; k < KK; ++k) {
        s_d[(0 * KK + k) * MP + l] = d0[k];
        s_d[(1 * KK + k) * MP + l] = d1[k];
        s_d[(2 * KK + k) * MP + l] = d2[k];
    }
    __syncthreads();

    const int lp1 = (l + 1 < MP) ? l + 1 : MP - 1;   // clamped; masked anyway
    float sc[KK];
#pragma unroll
    for (int k = 0; k < KK; ++k) {
        float t0 = (l >= 1) ? s_d[(0 * KK + k) * MP + l - 1] : 0.f;
        float t1 = s_d[(1 * KK + k) * MP + l];
        float t2 = s_d[(2 * KK + k) * MP + lp1];
        sc[k] = vl ? (t0 + t1 + t2) : -1e30f;
    }

    // softmax over L per k: wave butterfly + 8-wave LDS combine
    float mx[KK];
#pragma unroll
    for (int k = 0; k < KK; ++k) {
        float m = sc[k];
        for (int s = 32; s > 0; s >>= 1) m = fmaxf(m, __shfl_xor(m, s, 64));
        if (lane == 0) s_red[k * NWAVE + w] = m;
    }
    __syncthreads();
#pragma unroll
    for (int k = 0; k < KK; ++k) {
        float m = s_red[k * NWAVE + 0];
#pragma unroll
        for (int ww = 1; ww < NWAVE; ++ww) m = fmaxf(m, s_red[k * NWAVE + ww]);
        mx[k] = m;
    }
    __syncthreads();
    float ex[KK], sm[KK];
#pragma unroll
    for (int k = 0; k < KK; ++k) {
        ex[k] = __expf(sc[k] - mx[k]);   // pads: exp(-huge) = 0
        float s = ex[k];
        for (int sh = 32; sh > 0; sh >>= 1) s += __shfl_xor(s, sh, 64);
        if (lane == 0) s_red[k * NWAVE + w] = s;
    }
    __syncthreads();
#pragma unroll
    for (int k = 0; k < KK; ++k) {
        float s = 0.f;
#pragma unroll
        for (int ww = 0; ww < NWAVE; ++ww) s += s_red[k * NWAVE + ww];
        sm[k] = s;
    }

    // attn writes + rep reduction
#pragma unroll
    for (int k = 0; k < KK; ++k) {
        float wk = ex[k] / sm[k];        // 0 for pad threads
        if (vl) out[((size_t)b * KK + k) * LL + l] = wk;
#pragma unroll
        for (int h = 0; h < HH; ++h) {
            float v = pr[k * HH + h] * wk;
            for (int sh = 32; sh > 0; sh >>= 1) v += __shfl_xor(v, sh, 64);
            if (lane == 0) s_rep[w * NF + k * HH + h] = v;
        }
    }
    __syncthreads();
    if (tid < NF) {
        float s = 0.f;
#pragma unroll
        for (int ww = 0; ww < NWAVE; ++ww) s += s_rep[ww * NF + tid];
        out[(size_t)BB * KK * LL + (size_t)b * NF + tid] = s;
    }
}

extern "C" void kernel_launch(void* const* d_in, const int* in_sizes, int n_in,
                              void* d_out, int out_size, void* d_ws, size_t ws_size,
                              hipStream_t stream) {
    const float* review   = (const float*)d_in[0];  // (B,L,E)
    const float* aspProj  = (const float*)d_in[1];  // (K,E,H)
    const float* aspEmbed = (const float*)d_in[2];  // (K,3H)
    float* out = (float*)d_out;

    anr_mfma<<<dim3(BB), dim3(NT), 0, stream>>>(review, aspProj, aspEmbed, out);
}

// Round 4
// 247.525 us; speedup vs baseline: 1.4967x; 1.0049x over previous
//
#include <hip/hip_runtime.h>

#define BB 256
#define LL 500
#define EE 300
#define HH 10
#define KK 5
#define NF 50          // K*H output features
#define NT 512         // 8 waves
#define NWAVE 8

#define MP 512         // padded M rows per batch
#define CK 32          // K-chunk per stage
#define NCH 10         // 10*32 = 320 (K zero-padded 300->320)
#define AP 40          // A row stride (bf16): 32 + 8 pad; 80 B rows, 16B-aligned
#define BP 328         // Bt row stride (bf16): 320 + 8 pad; 656 B rows, 16B-aligned
#define PP 53          // proj row stride (fp32), odd -> conflict-free

// LDS overlay (bytes)
#define A1_OFF   (MP * AP * 2)                 // 40960 (A0 at 0)
#define B_OFF    (2 * MP * AP * 2)             // 81920
#define B_BYTES  (64 * BP * 2)                 // 41984 (ends 123904)
#define SD_OFF   (MP * PP * 4)                 // proj [0,108544); s_d after
#define RED_OFF  (SD_OFF + 3 * KK * MP * 4)    // 139264
#define REP_OFF  (RED_OFF + KK * NWAVE * 4)    // 139424
#define EMB_OFF  (REP_OFF + NWAVE * NF * 4)    // 141024 (above GEMM region: safe cross-phase)
#define SMEM_BYTES (EMB_OFF + KK * 3 * HH * 4) // 141624 < 163840

typedef __attribute__((ext_vector_type(8))) short short8;
typedef __attribute__((ext_vector_type(4))) float f32x4;

__device__ __forceinline__ unsigned int f2bf(float x) {
    // round-to-nearest-even fp32 -> bf16 (returned in low 16 bits)
    unsigned int u = __float_as_uint(x);
    return (u + 0x7FFFu + ((u >> 16) & 1u)) >> 16;
}

__global__ __launch_bounds__(NT, 2) void anr_mfma2(
    const float* __restrict__ review,    // (B, L, E)
    const float* __restrict__ aspProj,   // (K, E, H)
    const float* __restrict__ aspEmbed,  // (K, 3H), f = h*3 + offset
    float* __restrict__ out)             // [attn (B,K,L)] ++ [rep (B,K,H)]
{
    __shared__ __align__(16) char smem[SMEM_BYTES];
    short* B16   = (short*)(smem + B_OFF);
    float* proj  = (float*)smem;
    float* s_d   = (float*)(smem + SD_OFF);
    float* s_red = (float*)(smem + RED_OFF);
    float* s_rep = (float*)(smem + REP_OFF);
    float* s_emb = (float*)(smem + EMB_OFF);

    const int tid  = threadIdx.x;
    const int b    = blockIdx.x;
    const int lane = tid & 63;
    const int w    = tid >> 6;
    const int quad = lane >> 4;
    const int m16  = lane & 15;
    const int q    = tid & 7;            // float4 column within chunk
    const int r0   = tid >> 3;           // base row (0..63), rows r0+64*i

    // ---- phase 0: zero Bt (pure LDS, no vmem in flight -> free drain) ----
    for (int j = tid; j < B_BYTES / 4; j += NT)
        ((int*)(smem + B_OFF))[j] = 0;
    __syncthreads();

    // ---- phase 1: batched loads (Bt fill + aspEmbed + chunk0 A), all in flight ----
    float btv[30];
#pragma unroll
    for (int i = 0; i < 30; ++i) {
        int j = tid + NT * i;
        btv[i] = (j < KK * EE * HH) ? aspProj[j] : 0.f;
    }
    float embv = (tid < KK * 3 * HH) ? aspEmbed[tid] : 0.f;

    const float4* rev4 = (const float4*)review + (size_t)b * LL * (EE / 4);
    float4 ld[8];
#pragma unroll
    for (int i = 0; i < 8; ++i) {
        int r = r0 + 64 * i;
        float4 z = {0.f, 0.f, 0.f, 0.f};
        ld[i] = (r < LL) ? rev4[(size_t)r * 75 + q] : z;   // chunk 0: q < 75 always
    }

    // scatter Bt (waits only the oldest 30+1 loads; chunk0 A stays in flight)
#pragma unroll
    for (int i = 0; i < 30; ++i) {
        int j = tid + NT * i;
        if (j < KK * EE * HH) {
            int kasp = j / (EE * HH);
            int rr   = j - kasp * (EE * HH);
            int e    = rr / HH;
            int h    = rr - e * HH;
            B16[(kasp * HH + h) * BP + e] = (short)f2bf(btv[i]);
        }
    }
    if (tid < KK * 3 * HH) s_emb[tid] = embv;

    // store chunk0 A -> buf0
    {
        short* An = (short*)smem;
#pragma unroll
        for (int i = 0; i < 8; ++i) {
            int r = r0 + 64 * i;
            uint2 pk;
            pk.x = f2bf(ld[i].x) | (f2bf(ld[i].y) << 16);
            pk.y = f2bf(ld[i].z) | (f2bf(ld[i].w) << 16);
            *(uint2*)&An[r * AP + q * 4] = pk;
        }
    }
    __syncthreads();

    // ---- GEMM main loop: proj[512x50] = A[512x320] * Bt[64x320]^T ----
    f32x4 acc[4][4];
#pragma unroll
    for (int mi = 0; mi < 4; ++mi)
#pragma unroll
        for (int ni = 0; ni < 4; ++ni)
            acc[mi][ni] = (f32x4){0.f, 0.f, 0.f, 0.f};

#pragma unroll
    for (int c = 0; c < NCH; ++c) {
        // issue chunk c+1 loads (overlap with this chunk's mfma)
        if (c + 1 < NCH) {
            const int fqB = (c + 1) * 8;
#pragma unroll
            for (int i = 0; i < 8; ++i) {
                int r = r0 + 64 * i;
                float4 z = {0.f, 0.f, 0.f, 0.f};
                ld[i] = (r < LL && (fqB + q) < EE / 4)
                            ? rev4[(size_t)r * 75 + fqB + q] : z;
            }
        }
        // mfma on buf[c&1]
        const short* Ac = (const short*)smem + (c & 1) * (MP * AP);
        short8 af[4], bf[4];
#pragma unroll
        for (int mi = 0; mi < 4; ++mi)
            af[mi] = *(const short8*)&Ac[(w * 64 + mi * 16 + m16) * AP + quad * 8];
#pragma unroll
        for (int ni = 0; ni < 4; ++ni)
            bf[ni] = *(const short8*)&B16[(ni * 16 + m16) * BP + c * CK + quad * 8];
#pragma unroll
        for (int mi = 0; mi < 4; ++mi)
#pragma unroll
            for (int ni = 0; ni < 4; ++ni)
                acc[mi][ni] = __builtin_amdgcn_mfma_f32_16x16x32_bf16(
                    af[mi], bf[ni], acc[mi][ni], 0, 0, 0);
        // wait, convert, store chunk c+1 into the other buffer; one barrier/chunk
        if (c + 1 < NCH) {
            short* An = (short*)smem + ((c + 1) & 1) * (MP * AP);
#pragma unroll
            for (int i = 0; i < 8; ++i) {
                int r = r0 + 64 * i;
                uint2 pk;
                pk.x = f2bf(ld[i].x) | (f2bf(ld[i].y) << 16);
                pk.y = f2bf(ld[i].z) | (f2bf(ld[i].w) << 16);
                *(uint2*)&An[r * AP + q * 4] = pk;
            }
            __syncthreads();
        }
    }

    // ---- C fragments -> proj LDS (C/D: col = lane&15, row = quad*4 + reg) ----
    __syncthreads();                     // GEMM reads done before smem reuse
#pragma unroll
    for (int mi = 0; mi < 4; ++mi) {
#pragma unroll
        for (int ni = 0; ni < 4; ++ni) {
            int col = ni * 16 + m16;
            if (col < NF) {
                int row = w * 64 + mi * 16 + quad * 4;
#pragma unroll
                for (int r = 0; r < 4; ++r)
                    proj[(row + r) * PP + col] = acc[mi][ni][r];
            }
        }
    }
    __syncthreads();

    // ---- epilogue: thread = one sequence position l (R3-proven) ----
    const int l  = tid;
    const bool vl = (l < LL);            // pad rows have proj == 0 exactly

    float pr[NF];
#pragma unroll
    for (int f = 0; f < NF; ++f) pr[f] = proj[l * PP + f];

    float d0[KK], d1[KK], d2[KK];
#pragma unroll
    for (int k = 0; k < KK; ++k) {
        float a0 = 0.f, a1 = 0.f, a2 = 0.f;
#pragma unroll
        for (int h = 0; h < HH; ++h) {
            float x = pr[k * HH + h];
            a0 = fmaf(x, s_emb[k * 3 * HH + 3 * h + 0], a0);
            a1 = fmaf(x, s_emb[k * 3 * HH + 3 * h + 1], a1);
            a2 = fmaf(x, s_emb[k * 3 * HH + 3 * h + 2], a2);
        }
        d0[k] = a0; d1[k] = a1; d2[k] = a2;
    }
#pragma unroll
    for (int k = 0; k < KK; ++k) {
        s_d[(0 * KK + k) * MP + l] = d0[k];
        s_d[(1 * KK + k) * MP + l] = d1[k];
        s_d[(2 * KK + k) * MP + l] = d2[k];
    }
    __syncthreads();

    const int lp1 = (l + 1 < MP) ? l + 1 : MP - 1;
    float sc[KK];
#pragma unroll
    for (int k = 0; k < KK; ++k) {
        float t0 = (l >= 1) ? s_d[(0 * KK + k) * MP + l - 1] : 0.f;
        float t1 = s_d[(1 * KK + k) * MP + l];
        float t2 = s_d[(2 * KK + k) * MP + lp1];
        sc[k] = vl ? (t0 + t1 + t2) : -1e30f;
    }

    float mx[KK];
#pragma unroll
    for (int k = 0; k < KK; ++k) {
        float m = sc[k];
        for (int s = 32; s > 0; s >>= 1) m = fmaxf(m, __shfl_xor(m, s, 64));
        if (lane == 0) s_red[k * NWAVE + w] = m;
    }
    __syncthreads();
#pragma unroll
    for (int k = 0; k < KK; ++k) {
        float m = s_red[k * NWAVE + 0];
#pragma unroll
        for (int ww = 1; ww < NWAVE; ++ww) m = fmaxf(m, s_red[k * NWAVE + ww]);
        mx[k] = m;
    }
    __syncthreads();
    float ex[KK], sm[KK];
#pragma unroll
    for (int k = 0; k < KK; ++k) {
        ex[k] = __expf(sc[k] - mx[k]);
        float s = ex[k];
        for (int sh = 32; sh > 0; sh >>= 1) s += __shfl_xor(s, sh, 64);
        if (lane == 0) s_red[k * NWAVE + w] = s;
    }
    __syncthreads();
#pragma unroll
    for (int k = 0; k < KK; ++k) {
        float s = 0.f;
#pragma unroll
        for (int ww = 0; ww < NWAVE; ++ww) s += s_red[k * NWAVE + ww];
        sm[k] = s;
    }

#pragma unroll
    for (int k = 0; k < KK; ++k) {
        float wk = ex[k] / sm[k];
        if (vl) out[((size_t)b * KK + k) * LL + l] = wk;
#pragma unroll
        for (int h = 0; h < HH; ++h) {
            float v = pr[k * HH + h] * wk;
            for (int sh = 32; sh > 0; sh >>= 1) v += __shfl_xor(v, sh, 64);
            if (lane == 0) s_rep[w * NF + k * HH + h] = v;
        }
    }
    __syncthreads();
    if (tid < NF) {
        float s = 0.f;
#pragma unroll
        for (int ww = 0; ww < NWAVE; ++ww) s += s_rep[ww * NF + tid];
        out[(size_t)BB * KK * LL + (size_t)b * NF + tid] = s;
    }
}

extern "C" void kernel_launch(void* const* d_in, const int* in_sizes, int n_in,
                              void* d_out, int out_size, void* d_ws, size_t ws_size,
                              hipStream_t stream) {
    const float* review   = (const float*)d_in[0];  // (B,L,E)
    const float* aspProj  = (const float*)d_in[1];  // (K,E,H)
    const float* aspEmbed = (const float*)d_in[2];  // (K,3H)
    float* out = (float*)d_out;

    anr_mfma2<<<dim3(BB), dim3(NT), 0, stream>>>(review, aspProj, aspEmbed, out);
}

// Round 5
// 238.750 us; speedup vs baseline: 1.5517x; 1.0368x over previous
//
#include <hip/hip_runtime.h>

#define BB 256
#define LL 500
#define EE 300
#define HH 10
#define KK 5
#define NF 50          // K*H output features
#define NT 512         // 8 waves
#define NWAVE 8

#define MP 512         // padded M rows per batch
#define CK 32          // K-chunk per stage
#define NCH 10         // 10*32 = 320 (K zero-padded 300->320)
#define AP 40          // A row stride (bf16): 32 + 8 pad
#define BP 328         // Bt row stride (bf16): 320 + 8 pad
#define PP 53          // proj row stride (fp32), odd -> conflict-free
#define NR4 75         // float4 per review row
#define NA4 3750       // float4 in aspProj (15000 floats)

// LDS overlay (bytes)
#define B_OFF    (2 * MP * AP * 2)             // 81920 (A0 at 0, A1 at 40960)
#define B_BYTES  (64 * BP * 2)                 // 41984
#define SD_OFF   (MP * PP * 4)                 // proj [0,108544); s_d after
#define RED_OFF  (SD_OFF + 3 * KK * MP * 4)    // 139264
#define REP_OFF  (RED_OFF + KK * NWAVE * 4)
#define EMB_OFF  (REP_OFF + NWAVE * NF * 4)
#define SMEM_BYTES (EMB_OFF + KK * 3 * HH * 4) // 141624 < 163840

typedef __attribute__((ext_vector_type(8))) short short8;
typedef __attribute__((ext_vector_type(4))) float f32x4;

__device__ __forceinline__ unsigned int f2bf(float x) {
    unsigned int u = __float_as_uint(x);
    return (u + 0x7FFFu + ((u >> 16) & 1u)) >> 16;   // RNE fp32->bf16 (low 16)
}

__global__ __launch_bounds__(NT, 2) void anr_mfma3(
    const float* __restrict__ review,    // (B, L, E)
    const float* __restrict__ aspProj,   // (K, E, H)
    const float* __restrict__ aspEmbed,  // (K, 3H)
    float* __restrict__ out)             // [attn (B,K,L)] ++ [rep (B,K,H)]
{
    __shared__ __align__(16) char smem[SMEM_BYTES];
    short* B16   = (short*)(smem + B_OFF);
    float* proj  = (float*)smem;
    float* s_d   = (float*)(smem + SD_OFF);
    float* s_red = (float*)(smem + RED_OFF);
    float* s_rep = (float*)(smem + REP_OFF);
    float* s_emb = (float*)(smem + EMB_OFF);

    const int tid  = threadIdx.x;
    const int b    = blockIdx.x;
    const int lane = tid & 63;
    const int w    = tid >> 6;
    const int quad = lane >> 4;
    const int m16  = lane & 15;
    const int q    = tid & 7;            // float4 column within chunk
    const int r0   = tid >> 3;           // base row (0..63)

    // ---- phase 0: zero Bt ----
    for (int j = tid; j < B_BYTES / 4; j += NT)
        ((int*)(smem + B_OFF))[j] = 0;
    __syncthreads();

    // ---- phase 1: ALL loads unconditional (clamped addresses), batched ----
    // clamped per-thread row pointers (reused every chunk)
    const float4* rev4 = (const float4*)review + (size_t)b * LL * NR4;
    const float4* rp[8];
#pragma unroll
    for (int i = 0; i < 8; ++i) {
        int r = r0 + 64 * i;
        rp[i] = rev4 + (size_t)((r < LL) ? r : (LL - 1)) * NR4;
    }

    const float4* ap4 = (const float4*)aspProj;
    float4 bt[8];
#pragma unroll
    for (int i = 0; i < 8; ++i) {
        int idx = tid + NT * i;
        bt[i] = ap4[(idx < NA4) ? idx : (NA4 - 1)];
    }
    float embv = aspEmbed[(tid < KK * 3 * HH) ? tid : 0];
    float4 ld[8];
#pragma unroll
    for (int i = 0; i < 8; ++i) ld[i] = rp[i][q];        // chunk 0: q < 75 always

    // scatter Bt (guard the WRITE only; loads already in flight)
#pragma unroll
    for (int i = 0; i < 8; ++i) {
        int idx = tid + NT * i;
        if (idx < NA4) {
            float vv[4] = {bt[i].x, bt[i].y, bt[i].z, bt[i].w};
#pragma unroll
            for (int cm = 0; cm < 4; ++cm) {
                int jj   = 4 * idx + cm;                 // < 15000
                int kasp = jj / (EE * HH);
                int rr   = jj - kasp * (EE * HH);
                int e    = rr / HH;
                int h    = rr - e * HH;
                B16[(kasp * HH + h) * BP + e] = (short)f2bf(vv[cm]);
            }
        }
    }
    if (tid < KK * 3 * HH) s_emb[tid] = embv;

    // store chunk0 A -> buf0
    {
        short* An = (short*)smem;
#pragma unroll
        for (int i = 0; i < 8; ++i) {
            int r = r0 + 64 * i;                          // store at UNclamped row slot
            uint2 pk;
            pk.x = f2bf(ld[i].x) | (f2bf(ld[i].y) << 16);
            pk.y = f2bf(ld[i].z) | (f2bf(ld[i].w) << 16);
            *(uint2*)&An[r * AP + q * 4] = pk;
        }
    }
    __syncthreads();

    // ---- GEMM main loop ----
    f32x4 acc[4][4];
#pragma unroll
    for (int mi = 0; mi < 4; ++mi)
#pragma unroll
        for (int ni = 0; ni < 4; ++ni)
            acc[mi][ni] = (f32x4){0.f, 0.f, 0.f, 0.f};

#pragma unroll
    for (int c = 0; c < NCH; ++c) {
        // issue chunk c+1 loads (unconditional, clamped column)
        if (c + 1 < NCH) {
            int fq = 8 * (c + 1) + q;
            if (fq > NR4 - 1) fq = NR4 - 1;               // cols 300+ hit Bt zeros anyway
#pragma unroll
            for (int i = 0; i < 8; ++i) ld[i] = rp[i][fq];
        }
        // mfma on buf[c&1]
        const short* Ac = (const short*)smem + (c & 1) * (MP * AP);
        short8 af[4], bf[4];
#pragma unroll
        for (int mi = 0; mi < 4; ++mi)
            af[mi] = *(const short8*)&Ac[(w * 64 + mi * 16 + m16) * AP + quad * 8];
#pragma unroll
        for (int ni = 0; ni < 4; ++ni)
            bf[ni] = *(const short8*)&B16[(ni * 16 + m16) * BP + c * CK + quad * 8];
#pragma unroll
        for (int mi = 0; mi < 4; ++mi)
#pragma unroll
            for (int ni = 0; ni < 4; ++ni)
                acc[mi][ni] = __builtin_amdgcn_mfma_f32_16x16x32_bf16(
                    af[mi], bf[ni], acc[mi][ni], 0, 0, 0);
        // convert + store chunk c+1, one barrier per chunk
        if (c + 1 < NCH) {
            short* An = (short*)smem + ((c + 1) & 1) * (MP * AP);
#pragma unroll
            for (int i = 0; i < 8; ++i) {
                int r = r0 + 64 * i;
                uint2 pk;
                pk.x = f2bf(ld[i].x) | (f2bf(ld[i].y) << 16);
                pk.y = f2bf(ld[i].z) | (f2bf(ld[i].w) << 16);
                *(uint2*)&An[r * AP + q * 4] = pk;
            }
            __syncthreads();
        }
    }

    // ---- C fragments -> proj LDS (C/D: col = lane&15, row = quad*4 + reg) ----
    __syncthreads();
#pragma unroll
    for (int mi = 0; mi < 4; ++mi) {
#pragma unroll
        for (int ni = 0; ni < 4; ++ni) {
            int col = ni * 16 + m16;
            if (col < NF) {
                int row = w * 64 + mi * 16 + quad * 4;
#pragma unroll
                for (int r = 0; r < 4; ++r)
                    proj[(row + r) * PP + col] = acc[mi][ni][r];
            }
        }
    }
    __syncthreads();

    // ---- epilogue: thread = one sequence position l ----
    const int l  = tid;
    const bool vl = (l < LL);            // pad rows now contain garbage -> mask results

    float pr[NF];
#pragma unroll
    for (int f = 0; f < NF; ++f) pr[f] = proj[l * PP + f];

    float d0[KK], d1[KK], d2[KK];
#pragma unroll
    for (int k = 0; k < KK; ++k) {
        float a0 = 0.f, a1 = 0.f, a2 = 0.f;
#pragma unroll
        for (int h = 0; h < HH; ++h) {
            float x = pr[k * HH + h];
            a0 = fmaf(x, s_emb[k * 3 * HH + 3 * h + 0], a0);
            a1 = fmaf(x, s_emb[k * 3 * HH + 3 * h + 1], a1);
            a2 = fmaf(x, s_emb[k * 3 * HH + 3 * h + 2], a2);
        }
        d0[k] = vl ? a0 : 0.f;           // mask garbage pad rows (values only)
        d1[k] = vl ? a1 : 0.f;
        d2[k] = vl ? a2 : 0.f;
    }
#pragma unroll
    for (int k = 0; k < KK; ++k) {
        s_d[(0 * KK + k) * MP + l] = d0[k];
        s_d[(1 * KK + k) * MP + l] = d1[k];
        s_d[(2 * KK + k) * MP + l] = d2[k];
    }
    __syncthreads();

    const int lp1 = (l + 1 < MP) ? l + 1 : MP - 1;
    float sc[KK];
#pragma unroll
    for (int k = 0; k < KK; ++k) {
        float t0 = (l >= 1) ? s_d[(0 * KK + k) * MP + l - 1] : 0.f;
        float t1 = s_d[(1 * KK + k) * MP + l];
        float t2 = s_d[(2 * KK + k) * MP + lp1];
        sc[k] = vl ? (t0 + t1 + t2) : -1e30f;
    }

    float mx[KK];
#pragma unroll
    for (int k = 0; k < KK; ++k) {
        float m = sc[k];
        for (int s = 32; s > 0; s >>= 1) m = fmaxf(m, __shfl_xor(m, s, 64));
        if (lane == 0) s_red[k * NWAVE + w] = m;
    }
    __syncthreads();
#pragma unroll
    for (int k = 0; k < KK; ++k) {
        float m = s_red[k * NWAVE + 0];
#pragma unroll
        for (int ww = 1; ww < NWAVE; ++ww) m = fmaxf(m, s_red[k * NWAVE + ww]);
        mx[k] = m;
    }
    __syncthreads();
    float ex[KK], sm[KK];
#pragma unroll
    for (int k = 0; k < KK; ++k) {
        ex[k] = __expf(sc[k] - mx[k]);
        float s = ex[k];
        for (int sh = 32; sh > 0; sh >>= 1) s += __shfl_xor(s, sh, 64);
        if (lane == 0) s_red[k * NWAVE + w] = s;
    }
    __syncthreads();
#pragma unroll
    for (int k = 0; k < KK; ++k) {
        float s = 0.f;
#pragma unroll
        for (int ww = 0; ww < NWAVE; ++ww) s += s_red[k * NWAVE + ww];
        sm[k] = s;
    }

#pragma unroll
    for (int k = 0; k < KK; ++k) {
        float wk = ex[k] / sm[k];
        if (vl) out[((size_t)b * KK + k) * LL + l] = wk;
#pragma unroll
        for (int h = 0; h < HH; ++h) {
            float v = pr[k * HH + h] * wk;   // pads: garbage * 0 = 0 (finite)
            for (int sh = 32; sh > 0; sh >>= 1) v += __shfl_xor(v, sh, 64);
            if (lane == 0) s_rep[w * NF + k * HH + h] = v;
        }
    }
    __syncthreads();
    if (tid < NF) {
        float s = 0.f;
#pragma unroll
        for (int ww = 0; ww < NWAVE; ++ww) s += s_rep[ww * NF + tid];
        out[(size_t)BB * KK * LL + (size_t)b * NF + tid] = s;
    }
}

extern "C" void kernel_launch(void* const* d_in, const int* in_sizes, int n_in,
                              void* d_out, int out_size, void* d_ws, size_t ws_size,
                              hipStream_t stream) {
    const float* review   = (const float*)d_in[0];  // (B,L,E)
    const float* aspProj  = (const float*)d_in[1];  // (K,E,H)
    const float* aspEmbed = (const float*)d_in[2];  // (K,3H)
    float* out = (float*)d_out;

    anr_mfma3<<<dim3(BB), dim3(NT), 0, stream>>>(review, aspProj, aspEmbed, out);
}